// Round 16
// baseline (337.361 us; speedup 1.0000x reference)
//
#include <hip/hip_runtime.h>
#include <hip/hip_bf16.h>
#include <cmath>

#define NNODES 100000
#define NGRAPHS 64
#define SHIFT 9
#define NPB 512                  // nodes per bucket
#define NB 196                   // ceil(NNODES / NPB)
#define CAP 12288                // max edges per bucket region (exp 8192 +- ~90)
#define BIN_CHUNK 4096
#define HSTRIDE 136              // LDS row stride in shorts (272B; 68 dwords == 4 mod 32)
#define CONVBLK 6250             // (NNODES*64/4)/256

typedef __attribute__((ext_vector_type(8))) short bf16x8;
typedef __attribute__((ext_vector_type(4))) float f32x4;
typedef __attribute__((ext_vector_type(4))) unsigned int u32x4;

__device__ __forceinline__ float bf2f(unsigned short u) {
    unsigned int v = ((unsigned int)u) << 16;
    return __uint_as_float(v);
}
__device__ __forceinline__ unsigned short f2bf(float f) {
    unsigned int v = __float_as_uint(f);
    unsigned int r = (v + 0x7fffu + ((v >> 16) & 1u)) >> 16;
    return (unsigned short)r;
}

__device__ __forceinline__ void atomicMaxF(float* addr, float v) {
    if (v >= 0.f) atomicMax((int*)addr, __float_as_int(v));
    else          atomicMin((unsigned int*)addr, __float_as_uint(v));
}

__device__ __forceinline__ void pack_one(unsigned short* wp, const float* W, int K, int t) {
    int total = (K / 32) * 8 * 64;
    if (t >= total) return;
    int l = t & 63;
    int n0 = (t >> 6) & 7;
    int kp = t >> 9;
    unsigned short o[8];
#pragma unroll
    for (int j = 0; j < 8; ++j)
        o[j] = f2bf(W[(size_t)(kp * 32 + (l >> 4) * 8 + j) * 128 + n0 * 16 + (l & 15)]);
    *(u32x4*)(wp + (size_t)t * 8) = *(u32x4*)o;
}

// ---- one launch: x->bf16 convert | 6 weight packs | pool init | gcur init ----
__global__ __launch_bounds__(256) void setup_kernel(
        unsigned short* __restrict__ B0, const float* __restrict__ x,
        unsigned short* wp1, const float* g1w1,
        unsigned short* wp2, const float* g1w2,
        unsigned short* wp3, const float* g2w1,
        unsigned short* wp4, const float* g2w2,
        unsigned short* wp5, const float* g3w1,
        unsigned short* wp6, const float* g3w2,
        float* __restrict__ pooled, int* __restrict__ gcur) {
    int b = blockIdx.x;
    int t = threadIdx.x;
    if (b < CONVBLK) {                       // convert: 4 floats / thread
        int i = b * 256 + t;
        float4 v = ((const float4*)x)[i];
        unsigned short o[4] = { f2bf(v.x), f2bf(v.y), f2bf(v.z), f2bf(v.w) };
        ((uint2*)B0)[i] = *(uint2*)o;
        return;
    }
    b -= CONVBLK;
    if (b < 44) {                            // weight packs
        if (b < 4)       pack_one(wp1, g1w1, 64,  b * 256 + t);
        else if (b < 12) pack_one(wp2, g1w2, 128, (b - 4) * 256 + t);
        else if (b < 20) pack_one(wp3, g2w1, 128, (b - 12) * 256 + t);
        else if (b < 28) pack_one(wp4, g2w2, 128, (b - 20) * 256 + t);
        else if (b < 36) pack_one(wp5, g3w1, 128, (b - 28) * 256 + t);
        else             pack_one(wp6, g3w2, 128, (b - 36) * 256 + t);
        return;
    }
    b -= 44;
    if (b < 32) {                            // pooled = -inf
        pooled[b * 256 + t] = -INFINITY;
        return;
    }
    if (t < NB) gcur[t] = t * CAP;           // gcur init
}

// ---------------- CSR build (binned) ----------------
__global__ __launch_bounds__(256) void bin_kernel(unsigned int* __restrict__ binned,
                                                  int* __restrict__ gcur,
                                                  const int* __restrict__ ei, int E) {
    __shared__ int cnt[NB];
    __shared__ int gbase[NB];
    __shared__ int loff[NB];
    int t = threadIdx.x;
    int base = blockIdx.x * BIN_CHUNK;
    for (int i = t; i < NB; i += 256) { cnt[i] = 0; loff[i] = 0; }
    __syncthreads();
    unsigned int pk[16]; short bk[16]; int ne = 0;
#pragma unroll
    for (int i = 0; i < 16; ++i) {
        int e = base + t + i * 256;
        if (e < E) {
            int s = ei[e], d = ei[E + e];
            int b = d >> SHIFT;
            pk[ne] = ((unsigned int)s << SHIFT) | (unsigned int)(d & (NPB - 1));
            bk[ne] = (short)b;
            ne++;
            atomicAdd(&cnt[b], 1);
        }
    }
    __syncthreads();
    for (int i = t; i < NB; i += 256)
        gbase[i] = cnt[i] ? atomicAdd(&gcur[i], cnt[i]) : 0;
    __syncthreads();
    for (int i = 0; i < ne; ++i) {
        int b = bk[i];
        int pos = atomicAdd(&loff[b], 1);
        binned[gbase[b] + pos] = pk[i];
    }
}

// one block per bucket; computes its own global base from gcur
__global__ __launch_bounds__(256) void fill2_kernel(int* __restrict__ csr,
                                                    int* __restrict__ start,
                                                    const unsigned int* __restrict__ binned,
                                                    const int* __restrict__ gcur, int N) {
    __shared__ int cur[NPB];
    __shared__ int tsum[256];
    __shared__ int gbs[2];
    int b = blockIdx.x, t = threadIdx.x;
    int n0 = b << SHIFT;
    int nn = N - n0; if (nn > NPB) nn = NPB;
    int c = gcur[b] - b * CAP;
    if (t == 0) {
        int acc = 0, tot = 0;
        for (int i = 0; i < NB; ++i) {
            int ci = gcur[i] - i * CAP;
            if (i < b) acc += ci;
            tot += ci;
        }
        gbs[0] = acc; gbs[1] = tot;
    }
    const unsigned int* eb = binned + (size_t)b * CAP;
    for (int i = t; i < NPB; i += 256) cur[i] = 0;
    __syncthreads();
    int gb = gbs[0];
    for (int p = t; p < c; p += 256) atomicAdd(&cur[eb[p] & (NPB - 1)], 1);
    __syncthreads();
    int v[2]; int s = 0;
#pragma unroll
    for (int i = 0; i < 2; ++i) { v[i] = cur[t * 2 + i]; s += v[i]; }
    int x = s;
    tsum[t] = x;
    __syncthreads();
    for (int off = 1; off < 256; off <<= 1) {
        int y = (t >= off) ? tsum[t - off] : 0;
        __syncthreads();
        x += y;
        tsum[t] = x;
        __syncthreads();
    }
    int run = x - s + gb;
#pragma unroll
    for (int i = 0; i < 2; ++i) {
        int idx = t * 2 + i;
        cur[idx] = run;
        if (idx < nn) start[n0 + idx] = run;
        run += v[i];
    }
    __syncthreads();
    for (int p = t; p < c; p += 256) {
        unsigned int e = eb[p];
        int slot = atomicAdd(&cur[e & (NPB - 1)], 1);
        csr[slot] = (int)(e >> SHIFT);
    }
    if (t == 0 && b == 0) start[N] = gbs[1];
}

// ------- fused GIN layer: gather -> LDS -> relu(A@W1+b1)@W2+b2 [-> pool] -------
// 128 thr = 2 waves; each wave owns 16 rows via a private 16xHSTRIDE LDS slice.
// Gather neighbor loop: 8 independent loads in flight (4 partial-sum sets) to
// compensate for the capped wave count (N/16 waves, no oversubscription).
template<int K1, bool POOL>
__global__ __launch_bounds__(128) void fused_layer(const unsigned short* __restrict__ Hin,
                                                   const int* __restrict__ start,
                                                   const int* __restrict__ csr,
                                                   const unsigned short* __restrict__ Wp1,
                                                   const float* __restrict__ bias1,
                                                   const unsigned short* __restrict__ Wp2,
                                                   const float* __restrict__ bias2,
                                                   unsigned short* __restrict__ out,
                                                   const int* __restrict__ batch,
                                                   float* __restrict__ pooled, int M) {
    __shared__ unsigned short tile[32 * HSTRIDE];
    __shared__ unsigned int lmax[2][128];
    const int l = threadIdx.x & 63;
    const int w = threadIdx.x >> 6;
    const int rbase = blockIdx.x * 32 + w * 16;       // wave's first global row
    unsigned short* wt = tile + (w * 16) * HSTRIDE;   // wave-private LDS slice

    if (POOL) {
        for (int i = threadIdx.x; i < 256; i += 128)
            ((unsigned int*)lmax)[i] = 0x007fffffu;   // encode(-inf)
        __syncthreads();
    }

    // ---- gather phase: fill the wave's 16 rows ----
    constexpr int LANES = (K1 == 128) ? 16 : 8;  // lanes per row
    constexpr int RPP = 64 / LANES;              // rows per pass
    const int rg = l / LANES;
    const int ch = l % LANES;
    const unsigned short* hbb = Hin + ch * 8;
#pragma unroll
    for (int pass = 0; pass < 16 / RPP; ++pass) {
        int rloc = pass * RPP + rg;
        int row = rbase + rloc;
        int rowc = row < M ? row : M - 1;
        float a0[8], a1[8], a2[8], a3[8];
        {
            u32x4 v = *(const u32x4*)(hbb + (size_t)rowc * K1);
            const unsigned short* q = (const unsigned short*)&v;
#pragma unroll
            for (int i = 0; i < 8; ++i) { a0[i] = bf2f(q[i]); a1[i] = 0.f; a2[i] = 0.f; a3[i] = 0.f; }
        }
        int p0 = start[rowc], p1 = start[rowc + 1];
        int p = p0;
        for (; p + 8 <= p1; p += 8) {
            int j0 = csr[p],     j1 = csr[p + 1], j2 = csr[p + 2], j3 = csr[p + 3];
            int j4 = csr[p + 4], j5 = csr[p + 5], j6 = csr[p + 6], j7 = csr[p + 7];
            u32x4 v0 = *(const u32x4*)(hbb + (size_t)j0 * K1);
            u32x4 v1 = *(const u32x4*)(hbb + (size_t)j1 * K1);
            u32x4 v2 = *(const u32x4*)(hbb + (size_t)j2 * K1);
            u32x4 v3 = *(const u32x4*)(hbb + (size_t)j3 * K1);
            u32x4 v4 = *(const u32x4*)(hbb + (size_t)j4 * K1);
            u32x4 v5 = *(const u32x4*)(hbb + (size_t)j5 * K1);
            u32x4 v6 = *(const u32x4*)(hbb + (size_t)j6 * K1);
            u32x4 v7 = *(const u32x4*)(hbb + (size_t)j7 * K1);
            const unsigned short* q0 = (const unsigned short*)&v0;
            const unsigned short* q1 = (const unsigned short*)&v1;
            const unsigned short* q2 = (const unsigned short*)&v2;
            const unsigned short* q3 = (const unsigned short*)&v3;
            const unsigned short* q4 = (const unsigned short*)&v4;
            const unsigned short* q5 = (const unsigned short*)&v5;
            const unsigned short* q6 = (const unsigned short*)&v6;
            const unsigned short* q7 = (const unsigned short*)&v7;
#pragma unroll
            for (int i = 0; i < 8; ++i) a0[i] += bf2f(q0[i]);
#pragma unroll
            for (int i = 0; i < 8; ++i) a1[i] += bf2f(q1[i]);
#pragma unroll
            for (int i = 0; i < 8; ++i) a2[i] += bf2f(q2[i]);
#pragma unroll
            for (int i = 0; i < 8; ++i) a3[i] += bf2f(q3[i]);
#pragma unroll
            for (int i = 0; i < 8; ++i) a0[i] += bf2f(q4[i]);
#pragma unroll
            for (int i = 0; i < 8; ++i) a1[i] += bf2f(q5[i]);
#pragma unroll
            for (int i = 0; i < 8; ++i) a2[i] += bf2f(q6[i]);
#pragma unroll
            for (int i = 0; i < 8; ++i) a3[i] += bf2f(q7[i]);
        }
        for (; p + 4 <= p1; p += 4) {
            int j0 = csr[p], j1 = csr[p + 1], j2 = csr[p + 2], j3 = csr[p + 3];
            u32x4 v0 = *(const u32x4*)(hbb + (size_t)j0 * K1);
            u32x4 v1 = *(const u32x4*)(hbb + (size_t)j1 * K1);
            u32x4 v2 = *(const u32x4*)(hbb + (size_t)j2 * K1);
            u32x4 v3 = *(const u32x4*)(hbb + (size_t)j3 * K1);
            const unsigned short* q0 = (const unsigned short*)&v0;
            const unsigned short* q1 = (const unsigned short*)&v1;
            const unsigned short* q2 = (const unsigned short*)&v2;
            const unsigned short* q3 = (const unsigned short*)&v3;
#pragma unroll
            for (int i = 0; i < 8; ++i) a0[i] += bf2f(q0[i]);
#pragma unroll
            for (int i = 0; i < 8; ++i) a1[i] += bf2f(q1[i]);
#pragma unroll
            for (int i = 0; i < 8; ++i) a2[i] += bf2f(q2[i]);
#pragma unroll
            for (int i = 0; i < 8; ++i) a3[i] += bf2f(q3[i]);
        }
        for (; p < p1; ++p) {
            int j = csr[p];
            u32x4 v = *(const u32x4*)(hbb + (size_t)j * K1);
            const unsigned short* q = (const unsigned short*)&v;
#pragma unroll
            for (int i = 0; i < 8; ++i) a0[i] += bf2f(q[i]);
        }
        unsigned short o[8];
#pragma unroll
        for (int i = 0; i < 8; ++i) o[i] = f2bf((a0[i] + a1[i]) + (a2[i] + a3[i]));
        *(u32x4*)(wt + rloc * HSTRIDE + ch * 8) = *(u32x4*)o;
    }

    // ---- GEMM1: A-fragments from the wave's LDS slice ----
    const int kgrp = l >> 4;
    const int col = l & 15;
    f32x4 acc[8];
#pragma unroll
    for (int i = 0; i < 8; ++i) acc[i] = (f32x4){0.f, 0.f, 0.f, 0.f};
#pragma unroll
    for (int kp = 0; kp < K1 / 32; ++kp) {
        bf16x8 a = *(const bf16x8*)(wt + col * HSTRIDE + kp * 32 + kgrp * 8);
#pragma unroll
        for (int n0 = 0; n0 < 8; ++n0) {
            bf16x8 bfr = *(const bf16x8*)(Wp1 + ((size_t)(kp * 8 + n0) * 64 + l) * 8);
            acc[n0] = __builtin_amdgcn_mfma_f32_16x16x32_bf16(a, bfr, acc[n0], 0, 0, 0);
        }
    }

    // ---- intermediate (relu+bf16) overwrites the same wave slice ----
#pragma unroll
    for (int n0 = 0; n0 < 8; ++n0) {
        float bv = bias1[n0 * 16 + col];
#pragma unroll
        for (int r = 0; r < 4; ++r) {
            float v = acc[n0][r] + bv;
            v = fmaxf(v, 0.f);
            wt[(kgrp * 4 + r) * HSTRIDE + n0 * 16 + col] = f2bf(v);
        }
    }

    // ---- GEMM2 ----
    f32x4 acc2[8];
#pragma unroll
    for (int i = 0; i < 8; ++i) acc2[i] = (f32x4){0.f, 0.f, 0.f, 0.f};
#pragma unroll
    for (int kp = 0; kp < 4; ++kp) {
        bf16x8 a2 = *(const bf16x8*)(wt + col * HSTRIDE + kp * 32 + kgrp * 8);
#pragma unroll
        for (int n0 = 0; n0 < 8; ++n0) {
            bf16x8 bfr = *(const bf16x8*)(Wp2 + ((size_t)(kp * 8 + n0) * 64 + l) * 8);
            acc2[n0] = __builtin_amdgcn_mfma_f32_16x16x32_bf16(a2, bfr, acc2[n0], 0, 0, 0);
        }
    }

    const int mbase = rbase;
    if (POOL) {
        int g0 = batch[blockIdx.x * 32];
        int gi[4]; bool ok[4];
#pragma unroll
        for (int r = 0; r < 4; ++r) {
            int row = mbase + kgrp * 4 + r;
            ok[r] = (row < M);
            gi[r] = ok[r] ? (batch[row] - g0) : 0;
        }
#pragma unroll
        for (int n0 = 0; n0 < 8; ++n0) {
            int f = n0 * 16 + col;
            float bv = bias2[f];
#pragma unroll
            for (int r = 0; r < 4; ++r) {
                if (ok[r]) {
                    float v = acc2[n0][r] + bv;
                    unsigned int u = __float_as_uint(v);
                    unsigned int key = (u & 0x80000000u) ? ~u : (u | 0x80000000u);
                    atomicMax(&lmax[gi[r]][f], key);
                }
            }
        }
        __syncthreads();
        for (int i = threadIdx.x; i < 256; i += 128) {
            unsigned int key = ((unsigned int*)lmax)[i];
            unsigned int u2 = (key & 0x80000000u) ? (key & 0x7fffffffu) : ~key;
            float v = __uint_as_float(u2);
            int g = g0 + (i >> 7);
            if (g < NGRAPHS && key != 0x007fffffu)
                atomicMaxF(&pooled[g * 128 + (i & 127)], v);
        }
    } else {
#pragma unroll
        for (int n0 = 0; n0 < 8; ++n0) {
            float bv = bias2[n0 * 16 + col];
#pragma unroll
            for (int r = 0; r < 4; ++r) {
                int row = mbase + kgrp * 4 + r;
                if (row < M)
                    out[(size_t)row * 128 + n0 * 16 + col] = f2bf(acc2[n0][r] + bv);
            }
        }
    }
}

// ---------------- head ----------------
__global__ __launch_bounds__(64) void head_kernel(float* __restrict__ out,
                                                  const float* __restrict__ pooled,
                                                  const float* __restrict__ w1,
                                                  const float* __restrict__ b1,
                                                  const float* __restrict__ w2,
                                                  const float* __restrict__ b2) {
    int g = blockIdx.x, t = threadIdx.x;
    __shared__ float a[64];
    __shared__ float o[10];
    __shared__ float red[2];
    const float* pg = pooled + g * 128;
    float acc = b1[t];
    for (int k = 0; k < 128; ++k) acc = fmaf(pg[k], w1[k * 64 + t], acc);
    a[t] = fmaxf(acc, 0.f);
    __syncthreads();
    if (t < 10) {
        float s = b2[t];
        for (int k = 0; k < 64; ++k) s = fmaf(a[k], w2[k * 10 + t], s);
        o[t] = s;
    }
    __syncthreads();
    if (t == 0) {
        float m = -INFINITY;
        for (int c = 0; c < 10; ++c) m = fmaxf(m, o[c]);
        float se = 0.f;
        for (int c = 0; c < 10; ++c) se += expf(o[c] - m);
        red[0] = m;
        red[1] = logf(se);
    }
    __syncthreads();
    if (t < 10) out[g * 10 + t] = o[t] - red[0] - red[1];
}

extern "C" void kernel_launch(void* const* d_in, const int* in_sizes, int n_in,
                              void* d_out, int out_size, void* d_ws, size_t ws_size,
                              hipStream_t stream) {
    const float* x    = (const float*)d_in[0];
    const int* ei     = (const int*)d_in[1];
    const int* batch  = (const int*)d_in[2];
    const float* g1w1 = (const float*)d_in[3];  const float* g1b1 = (const float*)d_in[4];
    const float* g1w2 = (const float*)d_in[5];  const float* g1b2 = (const float*)d_in[6];
    const float* g2w1 = (const float*)d_in[7];  const float* g2b1 = (const float*)d_in[8];
    const float* g2w2 = (const float*)d_in[9];  const float* g2b2 = (const float*)d_in[10];
    const float* g3w1 = (const float*)d_in[11]; const float* g3b1 = (const float*)d_in[12];
    const float* g3w2 = (const float*)d_in[13]; const float* g3b2 = (const float*)d_in[14];
    const float* f1w  = (const float*)d_in[15]; const float* f1b  = (const float*)d_in[16];
    const float* f2w  = (const float*)d_in[17]; const float* f2b  = (const float*)d_in[18];
    float* out = (float*)d_out;

    const int N = NNODES;
    const int E = in_sizes[1] / 2;

    char* base = (char*)d_ws;
    auto alloc = [&](size_t bytes) { char* p = base; base += (bytes + 255) & ~(size_t)255; return p; };

    // B1 (layer-1 output, 25.6MB) aliases binned (NB*CAP*4 = 9.63MB):
    // binned is dead (consumed by fill2) before fused1 writes B1.
    char* shared_region = alloc((size_t)N * 128 * 2);
    unsigned short* B1 = (unsigned short*)shared_region;
    unsigned int* binned = (unsigned int*)shared_region;
    unsigned short* B2 = (unsigned short*)alloc((size_t)N * 128 * 2);
    unsigned short* B0 = (unsigned short*)alloc((size_t)N * 64 * 2);   // x bf16
    int* csr      = (int*)alloc((size_t)E * 4);
    int* start    = (int*)alloc((size_t)(N + 1) * 4);
    int* gcur     = (int*)alloc((size_t)(NB + 4) * 4);
    float* pooled = (float*)alloc((size_t)NGRAPHS * 128 * 4);
    unsigned short* wp1 = (unsigned short*)alloc((size_t)64 * 128 * 2);
    unsigned short* wp2 = (unsigned short*)alloc((size_t)128 * 128 * 2);
    unsigned short* wp3 = (unsigned short*)alloc((size_t)128 * 128 * 2);
    unsigned short* wp4 = (unsigned short*)alloc((size_t)128 * 128 * 2);
    unsigned short* wp5 = (unsigned short*)alloc((size_t)128 * 128 * 2);
    unsigned short* wp6 = (unsigned short*)alloc((size_t)128 * 128 * 2);

    // ---- setup (convert + packs + inits), then CSR build ----
    setup_kernel<<<CONVBLK + 44 + 32 + 1, 256, 0, stream>>>(
        B0, x, wp1, g1w1, wp2, g1w2, wp3, g2w1, wp4, g2w2, wp5, g3w1, wp6, g3w2,
        pooled, gcur);
    bin_kernel<<<(E + BIN_CHUNK - 1) / BIN_CHUNK, 256, 0, stream>>>(binned, gcur, ei, E);
    fill2_kernel<<<NB, 256, 0, stream>>>(csr, start, binned, gcur, N);

    const int pgrid = (N + 31) / 32;

    // ---- fused layers (gather -> LDS -> MLP; layer 3 pools in epilogue) ----
    fused_layer<64, false><<<pgrid, 128, 0, stream>>>(B0, start, csr, wp1, g1b1, wp2, g1b2, B1, batch, pooled, N);
    fused_layer<128, false><<<pgrid, 128, 0, stream>>>(B1, start, csr, wp3, g2b1, wp4, g2b2, B2, batch, pooled, N);
    fused_layer<128, true><<<pgrid, 128, 0, stream>>>(B2, start, csr, wp5, g3b1, wp6, g3b2, (unsigned short*)nullptr, batch, pooled, N);

    // ---- head ----
    head_kernel<<<NGRAPHS, 64, 0, stream>>>(out, pooled, f1w, f1b, f2w, f2b);
}

// Round 17
// 268.541 us; speedup vs baseline: 1.2563x; 1.2563x over previous
//
#include <hip/hip_runtime.h>
#include <hip/hip_bf16.h>
#include <cmath>

#define NNODES 100000
#define NGRAPHS 64
#define SHIFT 9
#define NPB 512                  // nodes per bucket
#define NB 196                   // ceil(NNODES / NPB)
#define CAP 12288                // max edges per bucket region (exp 8192 +- ~90)
#define BIN_CHUNK 4096
#define HSTRIDE 136              // LDS row stride in shorts (272B; 68 dwords == 4 mod 32)
#define CONVBLK 6250             // (NNODES*64/4)/256

typedef __attribute__((ext_vector_type(8))) short bf16x8;
typedef __attribute__((ext_vector_type(4))) float f32x4;
typedef __attribute__((ext_vector_type(4))) unsigned int u32x4;

__device__ __forceinline__ float bf2f(unsigned short u) {
    unsigned int v = ((unsigned int)u) << 16;
    return __uint_as_float(v);
}
__device__ __forceinline__ unsigned short f2bf(float f) {
    unsigned int v = __float_as_uint(f);
    unsigned int r = (v + 0x7fffu + ((v >> 16) & 1u)) >> 16;
    return (unsigned short)r;
}

__device__ __forceinline__ void atomicMaxF(float* addr, float v) {
    if (v >= 0.f) atomicMax((int*)addr, __float_as_int(v));
    else          atomicMin((unsigned int*)addr, __float_as_uint(v));
}

__device__ __forceinline__ void pack_one(unsigned short* wp, const float* W, int K, int t) {
    int total = (K / 32) * 8 * 64;
    if (t >= total) return;
    int l = t & 63;
    int n0 = (t >> 6) & 7;
    int kp = t >> 9;
    unsigned short o[8];
#pragma unroll
    for (int j = 0; j < 8; ++j)
        o[j] = f2bf(W[(size_t)(kp * 32 + (l >> 4) * 8 + j) * 128 + n0 * 16 + (l & 15)]);
    *(u32x4*)(wp + (size_t)t * 8) = *(u32x4*)o;
}

// ---- one launch: x->bf16 convert | 6 weight packs | pool init | gcur init ----
__global__ __launch_bounds__(256) void setup_kernel(
        unsigned short* __restrict__ B0, const float* __restrict__ x,
        unsigned short* wp1, const float* g1w1,
        unsigned short* wp2, const float* g1w2,
        unsigned short* wp3, const float* g2w1,
        unsigned short* wp4, const float* g2w2,
        unsigned short* wp5, const float* g3w1,
        unsigned short* wp6, const float* g3w2,
        float* __restrict__ pooled, int* __restrict__ gcur) {
    int b = blockIdx.x;
    int t = threadIdx.x;
    if (b < CONVBLK) {                       // convert: 4 floats / thread
        int i = b * 256 + t;
        float4 v = ((const float4*)x)[i];
        unsigned short o[4] = { f2bf(v.x), f2bf(v.y), f2bf(v.z), f2bf(v.w) };
        ((uint2*)B0)[i] = *(uint2*)o;
        return;
    }
    b -= CONVBLK;
    if (b < 44) {                            // weight packs
        if (b < 4)       pack_one(wp1, g1w1, 64,  b * 256 + t);
        else if (b < 12) pack_one(wp2, g1w2, 128, (b - 4) * 256 + t);
        else if (b < 20) pack_one(wp3, g2w1, 128, (b - 12) * 256 + t);
        else if (b < 28) pack_one(wp4, g2w2, 128, (b - 20) * 256 + t);
        else if (b < 36) pack_one(wp5, g3w1, 128, (b - 28) * 256 + t);
        else             pack_one(wp6, g3w2, 128, (b - 36) * 256 + t);
        return;
    }
    b -= 44;
    if (b < 32) {                            // pooled = -inf
        pooled[b * 256 + t] = -INFINITY;
        return;
    }
    if (t < NB) gcur[t] = t * CAP;           // gcur init
}

// ---------------- CSR build (binned) ----------------
__global__ __launch_bounds__(256) void bin_kernel(unsigned int* __restrict__ binned,
                                                  int* __restrict__ gcur,
                                                  const int* __restrict__ ei, int E) {
    __shared__ int cnt[NB];
    __shared__ int gbase[NB];
    __shared__ int loff[NB];
    int t = threadIdx.x;
    int base = blockIdx.x * BIN_CHUNK;
    for (int i = t; i < NB; i += 256) { cnt[i] = 0; loff[i] = 0; }
    __syncthreads();
    unsigned int pk[16]; short bk[16]; int ne = 0;
#pragma unroll
    for (int i = 0; i < 16; ++i) {
        int e = base + t + i * 256;
        if (e < E) {
            int s = ei[e], d = ei[E + e];
            int b = d >> SHIFT;
            pk[ne] = ((unsigned int)s << SHIFT) | (unsigned int)(d & (NPB - 1));
            bk[ne] = (short)b;
            ne++;
            atomicAdd(&cnt[b], 1);
        }
    }
    __syncthreads();
    for (int i = t; i < NB; i += 256)
        gbase[i] = cnt[i] ? atomicAdd(&gcur[i], cnt[i]) : 0;
    __syncthreads();
    for (int i = 0; i < ne; ++i) {
        int b = bk[i];
        int pos = atomicAdd(&loff[b], 1);
        binned[gbase[b] + pos] = pk[i];
    }
}

// one block per bucket; computes its own global base from gcur
__global__ __launch_bounds__(256) void fill2_kernel(int* __restrict__ csr,
                                                    int* __restrict__ start,
                                                    const unsigned int* __restrict__ binned,
                                                    const int* __restrict__ gcur, int N) {
    __shared__ int cur[NPB];
    __shared__ int tsum[256];
    __shared__ int gbs[2];
    int b = blockIdx.x, t = threadIdx.x;
    int n0 = b << SHIFT;
    int nn = N - n0; if (nn > NPB) nn = NPB;
    int c = gcur[b] - b * CAP;
    if (t == 0) {
        int acc = 0, tot = 0;
        for (int i = 0; i < NB; ++i) {
            int ci = gcur[i] - i * CAP;
            if (i < b) acc += ci;
            tot += ci;
        }
        gbs[0] = acc; gbs[1] = tot;
    }
    const unsigned int* eb = binned + (size_t)b * CAP;
    for (int i = t; i < NPB; i += 256) cur[i] = 0;
    __syncthreads();
    int gb = gbs[0];
    for (int p = t; p < c; p += 256) atomicAdd(&cur[eb[p] & (NPB - 1)], 1);
    __syncthreads();
    int v[2]; int s = 0;
#pragma unroll
    for (int i = 0; i < 2; ++i) { v[i] = cur[t * 2 + i]; s += v[i]; }
    int x = s;
    tsum[t] = x;
    __syncthreads();
    for (int off = 1; off < 256; off <<= 1) {
        int y = (t >= off) ? tsum[t - off] : 0;
        __syncthreads();
        x += y;
        tsum[t] = x;
        __syncthreads();
    }
    int run = x - s + gb;
#pragma unroll
    for (int i = 0; i < 2; ++i) {
        int idx = t * 2 + i;
        cur[idx] = run;
        if (idx < nn) start[n0 + idx] = run;
        run += v[i];
    }
    __syncthreads();
    for (int p = t; p < c; p += 256) {
        unsigned int e = eb[p];
        int slot = atomicAdd(&cur[e & (NPB - 1)], 1);
        csr[slot] = (int)(e >> SHIFT);
    }
    if (t == 0 && b == 0) start[N] = gbs[1];
}

// ------- fused GIN layer: gather -> LDS -> relu(A@W1+b1)@W2+b2 [-> pool] -------
// 256 thr = 4 waves, block owns 32 rows. GATHER: each wave fills only 8 rows
// (doubles grid wave count to N/8 = 12500 -> real oversubscription). MFMA:
// wave pair rgrp=w>>1 covers 16 rows; each wave computes 4 of 8 col-fragments
// (half=w&1) -> acc[4], VGPR stays at the r15 level. 2 barriers/layer.
template<int K1, bool POOL>
__global__ __launch_bounds__(256) void fused_layer(const unsigned short* __restrict__ Hin,
                                                   const int* __restrict__ start,
                                                   const int* __restrict__ csr,
                                                   const unsigned short* __restrict__ Wp1,
                                                   const float* __restrict__ bias1,
                                                   const unsigned short* __restrict__ Wp2,
                                                   const float* __restrict__ bias2,
                                                   unsigned short* __restrict__ out,
                                                   const int* __restrict__ batch,
                                                   float* __restrict__ pooled, int M) {
    __shared__ unsigned short tile[32 * HSTRIDE];
    __shared__ unsigned int lmax[2][128];
    const int l = threadIdx.x & 63;
    const int w = threadIdx.x >> 6;
    const int rbase = blockIdx.x * 32;                // block's first global row

    if (POOL) {
        ((unsigned int*)lmax)[threadIdx.x] = 0x007fffffu;   // encode(-inf)
    }

    // ---- gather phase: wave w fills block-local rows w*8 .. w*8+7 ----
    constexpr int LANES = (K1 == 128) ? 16 : 8;  // lanes per row
    constexpr int RPP = 64 / LANES;              // rows per pass
    const int rg = l / LANES;
    const int ch = l % LANES;
    const unsigned short* hbb = Hin + ch * 8;
#pragma unroll
    for (int pass = 0; pass < 8 / RPP; ++pass) {
        int rloc = w * 8 + pass * RPP + rg;
        int row = rbase + rloc;
        int rowc = row < M ? row : M - 1;
        float a0[8], a1[8];
        {
            u32x4 v = *(const u32x4*)(hbb + (size_t)rowc * K1);
            const unsigned short* q = (const unsigned short*)&v;
#pragma unroll
            for (int i = 0; i < 8; ++i) { a0[i] = bf2f(q[i]); a1[i] = 0.f; }
        }
        int p0 = start[rowc], p1 = start[rowc + 1];
        int p = p0;
        for (; p + 4 <= p1; p += 4) {
            int j0 = csr[p], j1 = csr[p + 1], j2 = csr[p + 2], j3 = csr[p + 3];
            u32x4 v0 = *(const u32x4*)(hbb + (size_t)j0 * K1);
            u32x4 v1 = *(const u32x4*)(hbb + (size_t)j1 * K1);
            u32x4 v2 = *(const u32x4*)(hbb + (size_t)j2 * K1);
            u32x4 v3 = *(const u32x4*)(hbb + (size_t)j3 * K1);
            const unsigned short* q0 = (const unsigned short*)&v0;
            const unsigned short* q1 = (const unsigned short*)&v1;
            const unsigned short* q2 = (const unsigned short*)&v2;
            const unsigned short* q3 = (const unsigned short*)&v3;
#pragma unroll
            for (int i = 0; i < 8; ++i) a0[i] += bf2f(q0[i]);
#pragma unroll
            for (int i = 0; i < 8; ++i) a1[i] += bf2f(q1[i]);
#pragma unroll
            for (int i = 0; i < 8; ++i) a0[i] += bf2f(q2[i]);
#pragma unroll
            for (int i = 0; i < 8; ++i) a1[i] += bf2f(q3[i]);
        }
        for (; p < p1; ++p) {
            int j = csr[p];
            u32x4 v = *(const u32x4*)(hbb + (size_t)j * K1);
            const unsigned short* q = (const unsigned short*)&v;
#pragma unroll
            for (int i = 0; i < 8; ++i) a0[i] += bf2f(q[i]);
        }
        unsigned short o[8];
#pragma unroll
        for (int i = 0; i < 8; ++i) o[i] = f2bf(a0[i] + a1[i]);
        *(u32x4*)(tile + rloc * HSTRIDE + ch * 8) = *(u32x4*)o;
    }
    __syncthreads();

    // ---- MFMA phase: wave pair rgrp covers 16 rows, wave computes 4 col-frags ----
    const int rgrp = w >> 1;
    const int half = w & 1;
    unsigned short* wt = tile + (rgrp * 16) * HSTRIDE;
    const int kgrp = l >> 4;
    const int col = l & 15;

    f32x4 acc[4];
#pragma unroll
    for (int i = 0; i < 4; ++i) acc[i] = (f32x4){0.f, 0.f, 0.f, 0.f};
#pragma unroll
    for (int kp = 0; kp < K1 / 32; ++kp) {
        bf16x8 a = *(const bf16x8*)(wt + col * HSTRIDE + kp * 32 + kgrp * 8);
#pragma unroll
        for (int n = 0; n < 4; ++n) {
            bf16x8 bfr = *(const bf16x8*)(Wp1 + ((size_t)(kp * 8 + half * 4 + n) * 64 + l) * 8);
            acc[n] = __builtin_amdgcn_mfma_f32_16x16x32_bf16(a, bfr, acc[n], 0, 0, 0);
        }
    }
    __syncthreads();   // gather reads of tile done everywhere before overwrite

    // ---- intermediate (relu+bf16) into own column half of own row group ----
#pragma unroll
    for (int n = 0; n < 4; ++n) {
        int f = (half * 4 + n) * 16 + col;
        float bv = bias1[f];
#pragma unroll
        for (int r = 0; r < 4; ++r) {
            float v = acc[n][r] + bv;
            v = fmaxf(v, 0.f);
            wt[(kgrp * 4 + r) * HSTRIDE + f] = f2bf(v);
        }
    }
    __syncthreads();   // both halves of each row written

    // ---- GEMM2 ----
    f32x4 acc2[4];
#pragma unroll
    for (int i = 0; i < 4; ++i) acc2[i] = (f32x4){0.f, 0.f, 0.f, 0.f};
#pragma unroll
    for (int kp = 0; kp < 4; ++kp) {
        bf16x8 a2 = *(const bf16x8*)(wt + col * HSTRIDE + kp * 32 + kgrp * 8);
#pragma unroll
        for (int n = 0; n < 4; ++n) {
            bf16x8 bfr = *(const bf16x8*)(Wp2 + ((size_t)(kp * 8 + half * 4 + n) * 64 + l) * 8);
            acc2[n] = __builtin_amdgcn_mfma_f32_16x16x32_bf16(a2, bfr, acc2[n], 0, 0, 0);
        }
    }

    const int mbase = rbase + rgrp * 16;
    if (POOL) {
        int g0 = batch[rbase];
        int gi[4]; bool ok[4];
#pragma unroll
        for (int r = 0; r < 4; ++r) {
            int row = mbase + kgrp * 4 + r;
            ok[r] = (row < M);
            gi[r] = ok[r] ? (batch[row] - g0) : 0;
        }
#pragma unroll
        for (int n = 0; n < 4; ++n) {
            int f = (half * 4 + n) * 16 + col;
            float bv = bias2[f];
#pragma unroll
            for (int r = 0; r < 4; ++r) {
                if (ok[r]) {
                    float v = acc2[n][r] + bv;
                    unsigned int u = __float_as_uint(v);
                    unsigned int key = (u & 0x80000000u) ? ~u : (u | 0x80000000u);
                    atomicMax(&lmax[gi[r]][f], key);
                }
            }
        }
        __syncthreads();
        int t = threadIdx.x;
        unsigned int key = ((unsigned int*)lmax)[t];
        unsigned int u2 = (key & 0x80000000u) ? (key & 0x7fffffffu) : ~key;
        float v = __uint_as_float(u2);
        int g = g0 + (t >> 7);
        if (g < NGRAPHS && key != 0x007fffffu)
            atomicMaxF(&pooled[g * 128 + (t & 127)], v);
    } else {
#pragma unroll
        for (int n = 0; n < 4; ++n) {
            int f = (half * 4 + n) * 16 + col;
            float bv = bias2[f];
#pragma unroll
            for (int r = 0; r < 4; ++r) {
                int row = mbase + kgrp * 4 + r;
                if (row < M)
                    out[(size_t)row * 128 + f] = f2bf(acc2[n][r] + bv);
            }
        }
    }
}

// ---------------- head ----------------
__global__ __launch_bounds__(64) void head_kernel(float* __restrict__ out,
                                                  const float* __restrict__ pooled,
                                                  const float* __restrict__ w1,
                                                  const float* __restrict__ b1,
                                                  const float* __restrict__ w2,
                                                  const float* __restrict__ b2) {
    int g = blockIdx.x, t = threadIdx.x;
    __shared__ float a[64];
    __shared__ float o[10];
    __shared__ float red[2];
    const float* pg = pooled + g * 128;
    float acc = b1[t];
    for (int k = 0; k < 128; ++k) acc = fmaf(pg[k], w1[k * 64 + t], acc);
    a[t] = fmaxf(acc, 0.f);
    __syncthreads();
    if (t < 10) {
        float s = b2[t];
        for (int k = 0; k < 64; ++k) s = fmaf(a[k], w2[k * 10 + t], s);
        o[t] = s;
    }
    __syncthreads();
    if (t == 0) {
        float m = -INFINITY;
        for (int c = 0; c < 10; ++c) m = fmaxf(m, o[c]);
        float se = 0.f;
        for (int c = 0; c < 10; ++c) se += expf(o[c] - m);
        red[0] = m;
        red[1] = logf(se);
    }
    __syncthreads();
    if (t < 10) out[g * 10 + t] = o[t] - red[0] - red[1];
}

extern "C" void kernel_launch(void* const* d_in, const int* in_sizes, int n_in,
                              void* d_out, int out_size, void* d_ws, size_t ws_size,
                              hipStream_t stream) {
    const float* x    = (const float*)d_in[0];
    const int* ei     = (const int*)d_in[1];
    const int* batch  = (const int*)d_in[2];
    const float* g1w1 = (const float*)d_in[3];  const float* g1b1 = (const float*)d_in[4];
    const float* g1w2 = (const float*)d_in[5];  const float* g1b2 = (const float*)d_in[6];
    const float* g2w1 = (const float*)d_in[7];  const float* g2b1 = (const float*)d_in[8];
    const float* g2w2 = (const float*)d_in[9];  const float* g2b2 = (const float*)d_in[10];
    const float* g3w1 = (const float*)d_in[11]; const float* g3b1 = (const float*)d_in[12];
    const float* g3w2 = (const float*)d_in[13]; const float* g3b2 = (const float*)d_in[14];
    const float* f1w  = (const float*)d_in[15]; const float* f1b  = (const float*)d_in[16];
    const float* f2w  = (const float*)d_in[17]; const float* f2b  = (const float*)d_in[18];
    float* out = (float*)d_out;

    const int N = NNODES;
    const int E = in_sizes[1] / 2;

    char* base = (char*)d_ws;
    auto alloc = [&](size_t bytes) { char* p = base; base += (bytes + 255) & ~(size_t)255; return p; };

    // B1 (layer-1 output, 25.6MB) aliases binned (NB*CAP*4 = 9.63MB):
    // binned is dead (consumed by fill2) before fused1 writes B1.
    char* shared_region = alloc((size_t)N * 128 * 2);
    unsigned short* B1 = (unsigned short*)shared_region;
    unsigned int* binned = (unsigned int*)shared_region;
    unsigned short* B2 = (unsigned short*)alloc((size_t)N * 128 * 2);
    unsigned short* B0 = (unsigned short*)alloc((size_t)N * 64 * 2);   // x bf16
    int* csr      = (int*)alloc((size_t)E * 4);
    int* start    = (int*)alloc((size_t)(N + 1) * 4);
    int* gcur     = (int*)alloc((size_t)(NB + 4) * 4);
    float* pooled = (float*)alloc((size_t)NGRAPHS * 128 * 4);
    unsigned short* wp1 = (unsigned short*)alloc((size_t)64 * 128 * 2);
    unsigned short* wp2 = (unsigned short*)alloc((size_t)128 * 128 * 2);
    unsigned short* wp3 = (unsigned short*)alloc((size_t)128 * 128 * 2);
    unsigned short* wp4 = (unsigned short*)alloc((size_t)128 * 128 * 2);
    unsigned short* wp5 = (unsigned short*)alloc((size_t)128 * 128 * 2);
    unsigned short* wp6 = (unsigned short*)alloc((size_t)128 * 128 * 2);

    // ---- setup (convert + packs + inits), then CSR build ----
    setup_kernel<<<CONVBLK + 44 + 32 + 1, 256, 0, stream>>>(
        B0, x, wp1, g1w1, wp2, g1w2, wp3, g2w1, wp4, g2w2, wp5, g3w1, wp6, g3w2,
        pooled, gcur);
    bin_kernel<<<(E + BIN_CHUNK - 1) / BIN_CHUNK, 256, 0, stream>>>(binned, gcur, ei, E);
    fill2_kernel<<<NB, 256, 0, stream>>>(csr, start, binned, gcur, N);

    const int pgrid = (N + 31) / 32;

    // ---- fused layers (gather -> LDS -> MLP; layer 3 pools in epilogue) ----
    fused_layer<64, false><<<pgrid, 256, 0, stream>>>(B0, start, csr, wp1, g1b1, wp2, g1b2, B1, batch, pooled, N);
    fused_layer<128, false><<<pgrid, 256, 0, stream>>>(B1, start, csr, wp3, g2b1, wp4, g2b2, B2, batch, pooled, N);
    fused_layer<128, true><<<pgrid, 256, 0, stream>>>(B2, start, csr, wp5, g3b1, wp6, g3b2, (unsigned short*)nullptr, batch, pooled, N);

    // ---- head ----
    head_kernel<<<NGRAPHS, 64, 0, stream>>>(out, pooled, f1w, f1b, f2w, f2b);
}